// Round 11
// baseline (243.710 us; speedup 1.0000x reference)
//
#include <hip/hip_runtime.h>
#include <stdint.h>

// Radius-graph edge list, B=4, N=2048, cutoff 5.0.
// Output [2, B*P] int32: compacted valid edges (ascending flat index), -1 pad.
//
// Round-16: cell list (r10, validated exact) RE-PARALLELIZED.
//   r10 failure mode (measured): 4 worker blocks on 4/256 CUs, per-point
//   serial scans -> 170 us at 2.9% occupancy. Algorithm right, mapping wrong.
//   Fix:
//   - work unit = (q, one-of-27-neighbor-cells): 221K tasks, avg ~6 pair
//     tests, max ~ max-cell-occupancy -> bounded straggler.
//   - 32 finder blocks (8/batch x 256 thr), each rebuilds the batch's cell
//     table in LDS redundantly (~1-2 us, 24 KB L2-hot reads) -> no cross-
//     block coupling; all build barriers intra-block.
//   - edges: global atomicAdd(&counts[cb]) for slot (12K atomics spread over
//     4096 lines; r8's poison was one line) + stash write. counts zeroed by
//     a 16 KB memset node.
//   - fill: 1024 dedicated blocks in the SAME kernel (grid 1056): finder
//     ~3-4 us hides under the ~11 us 67 MB -1 stream.
//   K2 scatter: r10 byte-identical (validated): early-exit, 16 KB prefix,
//   pf-rank order restore, exact brute-force fallback for cnt > kCap.
// Lessons pinned: r3 grid.sync 286us; r5 fence/nontemporal 233us; r6
// barrier-after-fill vmcnt drain; r8 same-line atomics; r9 closed-form
// decode 62us VALU-bound; r10 4-block cell list 170us occupancy-bound.

namespace {
constexpr int kB = 4;
constexpr int kN = 2048;
constexpr int kP = kN * (kN - 1) / 2;              // 2096128
constexpr long long kTotal = (long long)kB * kP;   // 8384512
constexpr float kCut2 = 25.0f;                     // 5.0^2
constexpr int kCap = 128;                          // stash slots per count-blk
constexpr int kCBlkPerB = 1024;                    // count-blocks per batch
constexpr int kNCBlk = kB * kCBlkPerB;             // 4096 count-blocks
constexpr int kCells = 17 * 17 * 17;               // 4913 (cell size 10)
constexpr int kNFPerB = 8;                         // finder blocks per batch
constexpr int kNF = kB * kNFPerB;                  // 32 finder blocks
constexpr int kQPerF = kN / kNFPerB;               // 256 q's per finder block
constexpr int kTasksPerF = kQPerF * 27;            // 6912
constexpr int kFillBlk = 1024;
constexpr int kGrid1 = kNF + kFillBlk;             // 1056
constexpr int kFillN4 = (int)(2 * kTotal / 4);     // 4192256 int4s
}  // namespace

// p in [0,P) -> (i,j), i<j, triu row-major (fallback path only).
__device__ __forceinline__ void decode_pair(int p, int& i, int& j) {
  float t = sqrtf((float)(16769025 - 8 * p));
  int ii = (int)((4095.0f - t) * 0.5f);
  ii = ii < 0 ? 0 : (ii > kN - 2 ? kN - 2 : ii);
  while (ii > 0 && (ii * (4095 - ii)) / 2 > p) --ii;
  while (ii < kN - 2 && ((ii + 1) * (4094 - ii)) / 2 <= p) ++ii;
  i = ii;
  j = ii + 1 + (p - (ii * (4095 - ii)) / 2);
}

__device__ __forceinline__ bool pair_test(const float* __restrict__ x, int b, int p,
                                          int& gi, int& gj) {
  int i, j;
  decode_pair(p, i, j);
  const float* xb = x + (size_t)b * kN * 3;
  float dx = xb[3 * i + 0] - xb[3 * j + 0];
  float dy = xb[3 * i + 1] - xb[3 * j + 1];
  float dz = xb[3 * i + 2] - xb[3 * j + 2];
  gi = b * kN + i;
  gj = b * kN + j;
  return dx * dx + dy * dy + dz * dz <= kCut2;
}

// Clamped cell coords. Clamping is monotone -> true pairs (|d|<=5/dim) still
// land in adjacent (or same) clamped cells. (Validated exact in r10.)
__device__ __forceinline__ void cell_xyz(float X, float Y, float Z, int& cx,
                                         int& cy, int& cz) {
  cx = (int)floorf(X * 0.1f) + 8;
  cy = (int)floorf(Y * 0.1f) + 8;
  cz = (int)floorf(Z * 0.1f) + 8;
  cx = cx < 0 ? 0 : (cx > 16 ? 16 : cx);
  cy = cy < 0 ? 0 : (cy > 16 ? 16 : cy);
  cz = cz < 0 ? 0 : (cz > 16 ? 16 : cz);
}

// ---------------------------------------------------------------------------
// K1: blocks 0..31 = finder (task-parallel cell search, redundant LDS build);
//     blocks 32..1055 = grid-stride -1 fill of the 67 MB output.
// ---------------------------------------------------------------------------
__global__ __launch_bounds__(256) void fill_find_kernel(
    const float* __restrict__ x, uint32_t* __restrict__ counts,
    int2* __restrict__ stash, int* __restrict__ out) {
  const int t = threadIdx.x;
  const int bid = blockIdx.x;

  __shared__ uint32_t cnt[kCells];     // counts -> place-cursor -> end
  __shared__ uint16_t cstart[kCells];  // cell start in sorted[]
  __shared__ uint16_t sorted[kN];      // point indices, cell-sorted
  __shared__ uint32_t wsum[4];

  if (bid >= kNF) {
    // Filler: grid-stride -1 over the whole [2, B*P] int32 output.
    const int4 m1 = make_int4(-1, -1, -1, -1);
    int4* o = (int4*)out;
    for (uint32_t idx = (uint32_t)(bid - kNF) * 256 + t; idx < (uint32_t)kFillN4;
         idx += (uint32_t)kFillBlk * 256)
      o[idx] = m1;
    return;
  }

  // ---- Finder block: batch b, q-range [sub*256, sub*256+256) ----
  const int b = bid >> 3;
  const int sub = bid & 7;
  const int lane = t & 63, wave = t >> 6;
  const float3* __restrict__ xb3 = (const float3*)(x + (size_t)b * kN * 3);

  // Build (redundant per block; all barriers intra-block).
  for (int c = t; c < kCells; c += 256) cnt[c] = 0;
  __syncthreads();

  int mycell[8];
#pragma unroll
  for (int q8 = 0; q8 < 8; ++q8) {
    const int idx = q8 * 256 + t;
    const float3 p = xb3[idx];
    int cx, cy, cz;
    cell_xyz(p.x, p.y, p.z, cx, cy, cz);
    mycell[q8] = (cx * 17 + cy) * 17 + cz;
    atomicAdd(&cnt[mycell[q8]], 1u);
  }
  __syncthreads();

  // Exclusive scan of 4913 cell counts (20 cells/thread; reads all complete
  // before the barrier, writes after -> no hazard).
  {
    uint32_t lc[20];
    uint32_t ssum = 0;
    const int c0 = t * 20;
#pragma unroll
    for (int z = 0; z < 20; ++z) {
      const int c = c0 + z;
      lc[z] = (c < kCells) ? cnt[c] : 0u;
      ssum += lc[z];
    }
    uint32_t run = ssum;  // inclusive wave scan of per-thread sums
    for (int o = 1; o < 64; o <<= 1) {
      uint32_t u = __shfl_up(run, o, 64);
      if (lane >= o) run += u;
    }
    if (lane == 63) wsum[wave] = run;
    __syncthreads();
    uint32_t wb = 0;
    for (int w = 0; w < 4; ++w)
      if (w < wave) wb += wsum[w];
    uint32_t excl = wb + run - ssum;
#pragma unroll
    for (int z = 0; z < 20; ++z) {
      const int c = c0 + z;
      if (c < kCells) {
        cstart[c] = (uint16_t)excl;
        cnt[c] = excl;  // place cursor
        excl += lc[z];
      }
    }
  }
  __syncthreads();

  // Counting-sort place pass.
#pragma unroll
  for (int q8 = 0; q8 < 8; ++q8) {
    const int idx = q8 * 256 + t;
    const uint32_t s = atomicAdd(&cnt[mycell[q8]], 1u);
    sorted[s] = (uint16_t)idx;
  }
  __syncthreads();  // cnt[c] is now end offset of cell c

  // Find: one task = (q, one of 27 neighbor cells). Bounded, balanced.
  const int qbase = sub << 8;
  for (int task = t; task < kTasksPerF; task += 256) {
    const int ql = task / 27;            // magic-mul division
    const int c27 = task - ql * 27;
    const int q = qbase + ql;
    const float3 pq = xb3[q];
    int cx, cy, cz;
    cell_xyz(pq.x, pq.y, pq.z, cx, cy, cz);
    const int ax = cx + c27 / 9 - 1;
    const int ay = cy + (c27 / 3) % 3 - 1;
    const int az = cz + c27 % 3 - 1;
    if (ax < 0 || ax > 16 || ay < 0 || ay > 16 || az < 0 || az > 16) continue;
    const int nc = (ax * 17 + ay) * 17 + az;
    const uint32_t sE = cnt[nc];
    const int gi = (b << 11) + q;
    for (uint32_t s = cstart[nc]; s < sE; ++s) {
      const int r = sorted[s];
      if (r <= q) continue;
      const float3 pr = xb3[r];
      const float dx = pq.x - pr.x, dy = pq.y - pr.y, dz = pq.z - pr.z;
      if (dx * dx + dy * dy + dz * dz <= kCut2) {
        const int pf = (q * (4095 - q)) / 2 + (r - q - 1);
        const int cb = (b << 10) + (pf >> 11);
        const uint32_t slot = atomicAdd(&counts[cb], 1u);
        if (slot < (uint32_t)kCap)
          stash[(size_t)cb * kCap + slot] = make_int2(gi, (b << 11) + r);
      }
    }
  }
}

// ---------------------------------------------------------------------------
// K2: scatter (r10, validated). Early-exit; prefix from 16 KB counts;
// pf-rank restores order; exact brute-force fallback if cnt > kCap.
// ---------------------------------------------------------------------------
__global__ __launch_bounds__(256) void scatter_kernel(
    const float* __restrict__ x, const uint32_t* __restrict__ counts,
    const int2* __restrict__ stash, int* __restrict__ out) {
  const int bid = blockIdx.x;
  const int t = threadIdx.x;

  const uint32_t cnt = counts[bid];
  if (cnt == 0) return;  // ~4090/4096 blocks

  const uint4* c4 = (const uint4*)counts;  // exactly 4096 entries
  uint32_t part = 0;
#pragma unroll
  for (int q = 0; q < 4; ++q) {
    uint4 v = c4[t * 4 + q];
    int i0 = t * 16 + q * 4;
    part += (i0 + 0 < bid) ? v.x : 0u;
    part += (i0 + 1 < bid) ? v.y : 0u;
    part += (i0 + 2 < bid) ? v.z : 0u;
    part += (i0 + 3 < bid) ? v.w : 0u;
  }
  for (int o = 32; o > 0; o >>= 1) part += __shfl_down(part, o, 64);
  __shared__ uint32_t wred[4];
  if ((t & 63) == 0) wred[t >> 6] = part;
  __syncthreads();
  if (t == 0) wred[0] = wred[0] + wred[1] + wred[2] + wred[3];
  __syncthreads();
  const uint32_t off = wred[0];

  if (cnt <= (uint32_t)kCap) {
    __shared__ int2 ebuf[kCap];
    __shared__ uint32_t pfb[kCap];
    for (uint32_t e = t; e < cnt; e += 256) {
      int2 v = stash[(size_t)bid * kCap + e];
      ebuf[e] = v;
      int i = v.x & 2047, j = v.y & 2047;
      pfb[e] = (uint32_t)((i * (4095 - i)) / 2 + (j - i - 1));
    }
    __syncthreads();
    for (uint32_t e = t; e < cnt; e += 256) {
      uint32_t mypf = pfb[e];
      uint32_t rank = 0;
      for (uint32_t f = 0; f < cnt; ++f) rank += (pfb[f] < mypf) ? 1u : 0u;
      out[off + rank] = ebuf[e].x;
      out[(size_t)kTotal + off + rank] = ebuf[e].y;
    }
    return;
  }

  // Fallback (cnt > kCap): exact ballot recompute of this count-block's
  // 2048-pair range.
  const int wave = t >> 6, lane = t & 63;
  const int b = bid >> 10;
  const int p0 = (bid & 1023) << 11;
  __shared__ uint32_t slot[32];
  unsigned long long masks[8];
  int gi[8], gj[8];
  bool fl[8];
#pragma unroll
  for (int k = 0; k < 8; ++k) {
    int p = p0 + k * 256 + t;
    fl[k] = (p < kP) && pair_test(x, b, p, gi[k], gj[k]);
    masks[k] = __ballot(fl[k]);
    if (lane == 0) slot[k * 4 + wave] = (uint32_t)__popcll(masks[k]);
  }
  __syncthreads();
  if (t == 0) {
    uint32_t run = 0;
    for (int s = 0; s < 32; ++s) {
      uint32_t c = slot[s];
      slot[s] = run;
      run += c;
    }
  }
  __syncthreads();
#pragma unroll
  for (int k = 0; k < 8; ++k) {
    if (fl[k]) {
      uint32_t pos = off + slot[k * 4 + wave] +
                     (uint32_t)__popcll(masks[k] & ((1ULL << lane) - 1ULL));
      out[pos] = gi[k];
      out[(size_t)kTotal + pos] = gj[k];
    }
  }
}

extern "C" void kernel_launch(void* const* d_in, const int* in_sizes, int n_in,
                              void* d_out, int out_size, void* d_ws, size_t ws_size,
                              hipStream_t stream) {
  const float* x = (const float*)d_in[0];
  int* out = (int*)d_out;
  uint32_t* counts = (uint32_t*)d_ws;           // [4096]
  int2* stash = (int2*)(counts + 4096);         // [4096 * 128] = 4 MB

  (void)hipMemsetAsync(counts, 0, kNCBlk * sizeof(uint32_t), stream);
  hipLaunchKernelGGL(fill_find_kernel, dim3(kGrid1), dim3(256), 0, stream, x,
                     counts, stash, out);
  hipLaunchKernelGGL(scatter_kernel, dim3(kNCBlk), dim3(256), 0, stream, x, counts,
                     stash, out);
}

// Round 12
// 59.406 us; speedup vs baseline: 4.1024x; 4.1024x over previous
//
#include <hip/hip_runtime.h>
#include <stdint.h>

// Radius-graph edge list, B=4, N=2048, cutoff 5.0.
// Output [2, B*P] int32: compacted valid edges (ascending flat index), -1 pad.
//
// Round-17: TILED brute force. The pair test itself is ~8 VALU ops (~1 us
// chip-wide for 8.4M pairs); every prior slow variant was paying for INDEX
// BOOKKEEPING, not testing:
//   r0/r8 incremental walk ~ 20-40 us (serial chain + divergent row advance)
//   r9 closed-form decode  ~ 40 us VALU (sqrt + fixup loops per pair)
//   r10/r11 cell list      ~ 170-240 us (per-lane serial candidate chase at
//                            ~350 cyc/candidate, wave-max imbalance)
// Tiling makes indices implicit: block = (batch, i-tile, j-tile); thread owns
// i = ti*256+t (pi in regs); j-tile in LDS SoA; 256-step inner loop with
// same-address LDS broadcast loads. Hits are rare (~12K/8.4M): exec-masked
// emission computes pf = C(i)+(j-i-1) and does a spread global atomicAdd
// (validated r11) + stash write.
//   K1 (1056 blk x 256): blocks 0-143 finder (4 batches x 36 tile-pairs),
//       blocks 144-1055 grid-stride -1 int4 fill of the 67 MB output.
//       Finder (~5 us) hides under the fill stream (~12 us).
//   K2 scatter (4096 blk x 256): BYTE-IDENTICAL to r10/r11 (validated):
//       early-exit, 16 KB prefix, pf-rank order restore, exact brute-force
//       fallback if cnt > kCap.
// Lessons pinned: r3 grid.sync 286us; r5 fence/nontemporal 233us; r6
// barrier-after-fill vmcnt drain; r8 same-line atomics +10us (spread is ok).

namespace {
constexpr int kB = 4;
constexpr int kN = 2048;
constexpr int kP = kN * (kN - 1) / 2;              // 2096128
constexpr long long kTotal = (long long)kB * kP;   // 8384512
constexpr float kCut2 = 25.0f;                     // 5.0^2
constexpr int kCap = 128;                          // stash slots per count-blk
constexpr int kNCBlk = 4096;                       // count-blocks (2048 pairs)
constexpr int kTile = 256;
constexpr int kNT = kN / kTile;                    // 8 tiles per dim
constexpr int kTPairs = kNT * (kNT + 1) / 2;       // 36 (ti <= tj)
constexpr int kNF = kB * kTPairs;                  // 144 finder blocks
constexpr int kFillBlk = 912;
constexpr int kGrid1 = kNF + kFillBlk;             // 1056
constexpr int kFillN4 = (int)(2 * kTotal / 4);     // 4192256 int4s
}  // namespace

// p in [0,P) -> (i,j), i<j, triu row-major (scatter fallback path only).
__device__ __forceinline__ void decode_pair(int p, int& i, int& j) {
  float t = sqrtf((float)(16769025 - 8 * p));
  int ii = (int)((4095.0f - t) * 0.5f);
  ii = ii < 0 ? 0 : (ii > kN - 2 ? kN - 2 : ii);
  while (ii > 0 && (ii * (4095 - ii)) / 2 > p) --ii;
  while (ii < kN - 2 && ((ii + 1) * (4094 - ii)) / 2 <= p) ++ii;
  i = ii;
  j = ii + 1 + (p - (ii * (4095 - ii)) / 2);
}

__device__ __forceinline__ bool pair_test(const float* __restrict__ x, int b, int p,
                                          int& gi, int& gj) {
  int i, j;
  decode_pair(p, i, j);
  const float* xb = x + (size_t)b * kN * 3;
  float dx = xb[3 * i + 0] - xb[3 * j + 0];
  float dy = xb[3 * i + 1] - xb[3 * j + 1];
  float dz = xb[3 * i + 2] - xb[3 * j + 2];
  gi = b * kN + i;
  gj = b * kN + j;
  return dx * dx + dy * dy + dz * dz <= kCut2;
}

// ---------------------------------------------------------------------------
// K1: blocks 0..143 = tiled finder; blocks 144..1055 = -1 fill stream.
// ---------------------------------------------------------------------------
__global__ __launch_bounds__(256) void fill_find_kernel(
    const float* __restrict__ x, uint32_t* __restrict__ counts,
    int2* __restrict__ stash, int* __restrict__ out) {
  const int t = threadIdx.x;
  const int bid = blockIdx.x;

  if (bid >= kNF) {
    // Filler: grid-stride -1 over the whole [2, B*P] int32 output. Stores
    // issue from cycle 0; nothing big follows them (no barrier trap).
    const int4 m1 = make_int4(-1, -1, -1, -1);
    int4* o = (int4*)out;
    for (uint32_t idx = (uint32_t)(bid - kNF) * 256 + t; idx < (uint32_t)kFillN4;
         idx += (uint32_t)kFillBlk * 256)
      o[idx] = m1;
    return;
  }

  // ---- Finder: block = (batch b, i-tile ti, j-tile tj), ti <= tj ----
  __shared__ float sx[kTile], sy[kTile], sz[kTile];

  const int b = bid / kTPairs;
  const int u = bid - b * kTPairs;
  int ti = 0, rowlen = kNT, acc = 0;
  while (acc + rowlen <= u) { acc += rowlen; --rowlen; ++ti; }
  const int tj = ti + (u - acc);

  const float3* __restrict__ xb3 = (const float3*)(x + (size_t)b * kN * 3);
  {
    const float3 pj = xb3[tj * kTile + t];
    sx[t] = pj.x;
    sy[t] = pj.y;
    sz[t] = pj.z;
  }
  const int i = ti * kTile + t;
  const float3 pi = xb3[i];
  __syncthreads();

  const int gib = b << 11;            // global point-index base of batch b
  const int jbase = tj * kTile;
  const uint32_t Ci = (uint32_t)((i * (4095 - i)) >> 1);  // C(i), < 2^21
  const int cbb = b << 10;            // count-block base of batch b
  const bool diag = (ti == tj);       // block-uniform

  // 256-step inner loop: same-address LDS broadcast reads, 8 VALU test, rare
  // exec-masked emission. No decode, no divergence, no pointer-chase.
#pragma unroll 4
  for (int jj = 0; jj < kTile; ++jj) {
    const float dx = pi.x - sx[jj];
    const float dy = pi.y - sy[jj];
    const float dz = pi.z - sz[jj];
    const float d2 = dx * dx + dy * dy + dz * dz;
    const bool hit = (d2 <= kCut2) && (!diag || jj > t);
    if (hit) {  // ~12K total across grid; compiler emits execz skip
      const int j = jbase + jj;
      const uint32_t pf = Ci + (uint32_t)(j - i - 1);
      const int cb = cbb + (int)(pf >> 11);
      const uint32_t slot = atomicAdd(&counts[cb], 1u);
      if (slot < (uint32_t)kCap)
        stash[(size_t)cb * kCap + slot] = make_int2(gib + i, gib + j);
    }
  }
}

// ---------------------------------------------------------------------------
// K2: scatter (r10/r11, validated twice). Early-exit; prefix from 16 KB
// counts; pf-rank restores order; exact brute-force fallback if cnt > kCap.
// ---------------------------------------------------------------------------
__global__ __launch_bounds__(256) void scatter_kernel(
    const float* __restrict__ x, const uint32_t* __restrict__ counts,
    const int2* __restrict__ stash, int* __restrict__ out) {
  const int bid = blockIdx.x;
  const int t = threadIdx.x;

  const uint32_t cnt = counts[bid];
  if (cnt == 0) return;  // ~4090/4096 blocks

  const uint4* c4 = (const uint4*)counts;  // exactly 4096 entries
  uint32_t part = 0;
#pragma unroll
  for (int q = 0; q < 4; ++q) {
    uint4 v = c4[t * 4 + q];
    int i0 = t * 16 + q * 4;
    part += (i0 + 0 < bid) ? v.x : 0u;
    part += (i0 + 1 < bid) ? v.y : 0u;
    part += (i0 + 2 < bid) ? v.z : 0u;
    part += (i0 + 3 < bid) ? v.w : 0u;
  }
  for (int o = 32; o > 0; o >>= 1) part += __shfl_down(part, o, 64);
  __shared__ uint32_t wred[4];
  if ((t & 63) == 0) wred[t >> 6] = part;
  __syncthreads();
  if (t == 0) wred[0] = wred[0] + wred[1] + wred[2] + wred[3];
  __syncthreads();
  const uint32_t off = wred[0];

  if (cnt <= (uint32_t)kCap) {
    __shared__ int2 ebuf[kCap];
    __shared__ uint32_t pfb[kCap];
    for (uint32_t e = t; e < cnt; e += 256) {
      int2 v = stash[(size_t)bid * kCap + e];
      ebuf[e] = v;
      int i = v.x & 2047, j = v.y & 2047;
      pfb[e] = (uint32_t)((i * (4095 - i)) / 2 + (j - i - 1));
    }
    __syncthreads();
    for (uint32_t e = t; e < cnt; e += 256) {
      uint32_t mypf = pfb[e];
      uint32_t rank = 0;
      for (uint32_t f = 0; f < cnt; ++f) rank += (pfb[f] < mypf) ? 1u : 0u;
      out[off + rank] = ebuf[e].x;
      out[(size_t)kTotal + off + rank] = ebuf[e].y;
    }
    return;
  }

  // Fallback (cnt > kCap): exact ballot recompute of this count-block's
  // 2048-pair range.
  const int wave = t >> 6, lane = t & 63;
  const int b = bid >> 10;
  const int p0 = (bid & 1023) << 11;
  __shared__ uint32_t slot[32];
  unsigned long long masks[8];
  int gi[8], gj[8];
  bool fl[8];
#pragma unroll
  for (int k = 0; k < 8; ++k) {
    int p = p0 + k * 256 + t;
    fl[k] = (p < kP) && pair_test(x, b, p, gi[k], gj[k]);
    masks[k] = __ballot(fl[k]);
    if (lane == 0) slot[k * 4 + wave] = (uint32_t)__popcll(masks[k]);
  }
  __syncthreads();
  if (t == 0) {
    uint32_t run = 0;
    for (int s = 0; s < 32; ++s) {
      uint32_t c = slot[s];
      slot[s] = run;
      run += c;
    }
  }
  __syncthreads();
#pragma unroll
  for (int k = 0; k < 8; ++k) {
    if (fl[k]) {
      uint32_t pos = off + slot[k * 4 + wave] +
                     (uint32_t)__popcll(masks[k] & ((1ULL << lane) - 1ULL));
      out[pos] = gi[k];
      out[(size_t)kTotal + pos] = gj[k];
    }
  }
}

extern "C" void kernel_launch(void* const* d_in, const int* in_sizes, int n_in,
                              void* d_out, int out_size, void* d_ws, size_t ws_size,
                              hipStream_t stream) {
  const float* x = (const float*)d_in[0];
  int* out = (int*)d_out;
  uint32_t* counts = (uint32_t*)d_ws;           // [4096]
  int2* stash = (int2*)(counts + 4096);         // [4096 * 128] = 4 MB

  (void)hipMemsetAsync(counts, 0, kNCBlk * sizeof(uint32_t), stream);
  hipLaunchKernelGGL(fill_find_kernel, dim3(kGrid1), dim3(256), 0, stream, x,
                     counts, stash, out);
  hipLaunchKernelGGL(scatter_kernel, dim3(kNCBlk), dim3(256), 0, stream, x, counts,
                     stash, out);
}

// Round 13
// 48.391 us; speedup vs baseline: 5.0363x; 1.2276x over previous
//
#include <hip/hip_runtime.h>
#include <stdint.h>

// Radius-graph edge list, B=4, N=2048, cutoff 5.0.
// Output [2, B*P] int32: compacted valid edges (ascending flat index), -1 pad.
//
// Round-18: r12's tiled brute force with the finder inner loop RESTRUCTURED
// for latency. r12 measured: K1 45.5 us, occupancy 8.4% (= finder straggler:
// fill waves retired early), VALUBusy 5.2% (= finder 95% stalled), ~400
// cyc/iter = 3 dependent ds_read_b32 at full ~130 cy LDS latency per pair,
// no TLP (1 wave/SIMD), no ILP (atomic in loop body blocks pipelining).
// Fix: float4 LDS (1 ds_read_b128/candidate), register DOUBLE-BUFFER batches
// of 8 (test batch k while batch k+1 loads; LDS on lgkmcnt, atomic on vmcnt
// -> emission never drains prefetch), emission gated per-8 by bitmask.
//   K1 (2192 blk x 256): blocks 0-143 finder (4 batches x 36 tile-pairs,
//       256x256 tests each), blocks 144-2191 contiguous-chunk -1 fill.
//   K2 scatter (4096 blk x 256): BYTE-IDENTICAL to r10/r11/r12 (validated
//       3x): early-exit, 16 KB prefix, pf-rank order restore, exact
//       brute-force fallback if cnt > kCap.
// Lessons pinned: r3 grid.sync 286us; r5 fence/nontemporal 233us; r6
// barrier-after-fill vmcnt drain; r8 same-line atomics; r9 decode VALU-bound;
// r10/r11 cell-list pointer-chase; r12 LDS-latency serial inner loop.

namespace {
constexpr int kB = 4;
constexpr int kN = 2048;
constexpr int kP = kN * (kN - 1) / 2;              // 2096128
constexpr long long kTotal = (long long)kB * kP;   // 8384512
constexpr float kCut2 = 25.0f;                     // 5.0^2
constexpr int kCap = 128;                          // stash slots per count-blk
constexpr int kNCBlk = 4096;                       // count-blocks (2048 pairs)
constexpr int kTile = 256;
constexpr int kNT = kN / kTile;                    // 8 tiles per dim
constexpr int kTPairs = kNT * (kNT + 1) / 2;       // 36 (ti <= tj)
constexpr int kNF = kB * kTPairs;                  // 144 finder blocks
constexpr int kFillBlk = 2048;
constexpr int kGrid1 = kNF + kFillBlk;             // 2192
constexpr int kFillN4 = (int)(2 * kTotal / 4);     // 4192256 int4s
constexpr int kFillPerBlk = 2048;                  // int4s per fill block
}  // namespace

// p in [0,P) -> (i,j), i<j, triu row-major (scatter fallback path only).
__device__ __forceinline__ void decode_pair(int p, int& i, int& j) {
  float t = sqrtf((float)(16769025 - 8 * p));
  int ii = (int)((4095.0f - t) * 0.5f);
  ii = ii < 0 ? 0 : (ii > kN - 2 ? kN - 2 : ii);
  while (ii > 0 && (ii * (4095 - ii)) / 2 > p) --ii;
  while (ii < kN - 2 && ((ii + 1) * (4094 - ii)) / 2 <= p) ++ii;
  i = ii;
  j = ii + 1 + (p - (ii * (4095 - ii)) / 2);
}

__device__ __forceinline__ bool pair_test(const float* __restrict__ x, int b, int p,
                                          int& gi, int& gj) {
  int i, j;
  decode_pair(p, i, j);
  const float* xb = x + (size_t)b * kN * 3;
  float dx = xb[3 * i + 0] - xb[3 * j + 0];
  float dy = xb[3 * i + 1] - xb[3 * j + 1];
  float dz = xb[3 * i + 2] - xb[3 * j + 2];
  gi = b * kN + i;
  gj = b * kN + j;
  return dx * dx + dy * dy + dz * dz <= kCut2;
}

// ---------------------------------------------------------------------------
// K1: blocks 0..143 = tiled finder (pipelined); blocks 144.. = -1 fill.
// ---------------------------------------------------------------------------
__global__ __launch_bounds__(256) void fill_find_kernel(
    const float* __restrict__ x, uint32_t* __restrict__ counts,
    int2* __restrict__ stash, int* __restrict__ out) {
  const int t = threadIdx.x;
  const int bid = blockIdx.x;

  if (bid >= kNF) {
    // Filler: contiguous 32 KB chunk of -1 per block; stores issue from
    // cycle 0, nothing follows them (no barrier trap).
    const int4 m1 = make_int4(-1, -1, -1, -1);
    int4* o = (int4*)out;
    const int base = (bid - kNF) * kFillPerBlk;
#pragma unroll
    for (int s = 0; s < 8; ++s) {
      const int idx = base + s * 256 + t;
      if (idx < kFillN4) o[idx] = m1;
    }
    return;
  }

  // ---- Finder: block = (batch b, i-tile ti, j-tile tj), ti <= tj ----
  __shared__ float4 sp[kTile];  // j-tile, float4 -> one ds_read_b128/cand

  const int b = bid / kTPairs;
  const int u = bid - b * kTPairs;
  int ti = 0, rowlen = kNT, acc = 0;
  while (acc + rowlen <= u) { acc += rowlen; --rowlen; ++ti; }
  const int tj = ti + (u - acc);

  const float3* __restrict__ xb3 = (const float3*)(x + (size_t)b * kN * 3);
  {
    const float3 pj = xb3[tj * kTile + t];
    sp[t] = make_float4(pj.x, pj.y, pj.z, 0.0f);
  }
  const int i = ti * kTile + t;
  const float3 pi = xb3[i];
  __syncthreads();

  const int gib = b << 11;            // global point-index base of batch b
  const int jbase = tj * kTile;
  const uint32_t Ci = (uint32_t)((i * (4095 - i)) >> 1);  // C(i)
  const int cbb = b << 10;            // count-block base of batch b
  const bool diag = (ti == tj);       // block-uniform

  // Emission: rare (~83 edges/finder-block). atomic is vmcnt; LDS prefetch
  // (lgkmcnt) is NOT drained by it.
  auto emit = [&](uint32_t m, int jb0) {
    do {
      const int k = __ffs(m) - 1;
      m &= m - 1;
      const int j = jbase + jb0 + k;
      const uint32_t pf = Ci + (uint32_t)(j - i - 1);
      const int cb = cbb + (int)(pf >> 11);
      const uint32_t slot = atomicAdd(&counts[cb], 1u);
      if (slot < (uint32_t)kCap)
        stash[(size_t)cb * kCap + slot] = make_int2(gib + i, gib + j);
    } while (m);
  };

  // Register double-buffered batches of 8: test A while B loads.
  float4 A[8], Bv[8];
#pragma unroll
  for (int k = 0; k < 8; ++k) A[k] = sp[k];

#pragma unroll
  for (int jb = 0; jb < kTile; jb += 16) {
#pragma unroll
    for (int k = 0; k < 8; ++k) Bv[k] = sp[jb + 8 + k];  // prefetch next 8
    uint32_t m = 0;
#pragma unroll
    for (int k = 0; k < 8; ++k) {
      const float dx = pi.x - A[k].x;
      const float dy = pi.y - A[k].y;
      const float dz = pi.z - A[k].z;
      const bool hit =
          (dx * dx + dy * dy + dz * dz <= kCut2) && (!diag || (jb + k) > t);
      m |= (uint32_t)hit << k;
    }
    if (m) emit(m, jb);

    if (jb + 16 < kTile) {
#pragma unroll
      for (int k = 0; k < 8; ++k) A[k] = sp[jb + 16 + k];  // prefetch next 8
    }
    m = 0;
#pragma unroll
    for (int k = 0; k < 8; ++k) {
      const float dx = pi.x - Bv[k].x;
      const float dy = pi.y - Bv[k].y;
      const float dz = pi.z - Bv[k].z;
      const bool hit =
          (dx * dx + dy * dy + dz * dz <= kCut2) && (!diag || (jb + 8 + k) > t);
      m |= (uint32_t)hit << k;
    }
    if (m) emit(m, jb + 8);
  }
}

// ---------------------------------------------------------------------------
// K2: scatter (r10/r11/r12, validated 3x). Early-exit; prefix from 16 KB
// counts; pf-rank restores order; exact brute-force fallback if cnt > kCap.
// ---------------------------------------------------------------------------
__global__ __launch_bounds__(256) void scatter_kernel(
    const float* __restrict__ x, const uint32_t* __restrict__ counts,
    const int2* __restrict__ stash, int* __restrict__ out) {
  const int bid = blockIdx.x;
  const int t = threadIdx.x;

  const uint32_t cnt = counts[bid];
  if (cnt == 0) return;  // ~4090/4096 blocks

  const uint4* c4 = (const uint4*)counts;  // exactly 4096 entries
  uint32_t part = 0;
#pragma unroll
  for (int q = 0; q < 4; ++q) {
    uint4 v = c4[t * 4 + q];
    int i0 = t * 16 + q * 4;
    part += (i0 + 0 < bid) ? v.x : 0u;
    part += (i0 + 1 < bid) ? v.y : 0u;
    part += (i0 + 2 < bid) ? v.z : 0u;
    part += (i0 + 3 < bid) ? v.w : 0u;
  }
  for (int o = 32; o > 0; o >>= 1) part += __shfl_down(part, o, 64);
  __shared__ uint32_t wred[4];
  if ((t & 63) == 0) wred[t >> 6] = part;
  __syncthreads();
  if (t == 0) wred[0] = wred[0] + wred[1] + wred[2] + wred[3];
  __syncthreads();
  const uint32_t off = wred[0];

  if (cnt <= (uint32_t)kCap) {
    __shared__ int2 ebuf[kCap];
    __shared__ uint32_t pfb[kCap];
    for (uint32_t e = t; e < cnt; e += 256) {
      int2 v = stash[(size_t)bid * kCap + e];
      ebuf[e] = v;
      int i = v.x & 2047, j = v.y & 2047;
      pfb[e] = (uint32_t)((i * (4095 - i)) / 2 + (j - i - 1));
    }
    __syncthreads();
    for (uint32_t e = t; e < cnt; e += 256) {
      uint32_t mypf = pfb[e];
      uint32_t rank = 0;
      for (uint32_t f = 0; f < cnt; ++f) rank += (pfb[f] < mypf) ? 1u : 0u;
      out[off + rank] = ebuf[e].x;
      out[(size_t)kTotal + off + rank] = ebuf[e].y;
    }
    return;
  }

  // Fallback (cnt > kCap): exact ballot recompute of this count-block's
  // 2048-pair range.
  const int wave = t >> 6, lane = t & 63;
  const int b = bid >> 10;
  const int p0 = (bid & 1023) << 11;
  __shared__ uint32_t slot[32];
  unsigned long long masks[8];
  int gi[8], gj[8];
  bool fl[8];
#pragma unroll
  for (int k = 0; k < 8; ++k) {
    int p = p0 + k * 256 + t;
    fl[k] = (p < kP) && pair_test(x, b, p, gi[k], gj[k]);
    masks[k] = __ballot(fl[k]);
    if (lane == 0) slot[k * 4 + wave] = (uint32_t)__popcll(masks[k]);
  }
  __syncthreads();
  if (t == 0) {
    uint32_t run = 0;
    for (int s = 0; s < 32; ++s) {
      uint32_t c = slot[s];
      slot[s] = run;
      run += c;
    }
  }
  __syncthreads();
#pragma unroll
  for (int k = 0; k < 8; ++k) {
    if (fl[k]) {
      uint32_t pos = off + slot[k * 4 + wave] +
                     (uint32_t)__popcll(masks[k] & ((1ULL << lane) - 1ULL));
      out[pos] = gi[k];
      out[(size_t)kTotal + pos] = gj[k];
    }
  }
}

extern "C" void kernel_launch(void* const* d_in, const int* in_sizes, int n_in,
                              void* d_out, int out_size, void* d_ws, size_t ws_size,
                              hipStream_t stream) {
  const float* x = (const float*)d_in[0];
  int* out = (int*)d_out;
  uint32_t* counts = (uint32_t*)d_ws;           // [4096]
  int2* stash = (int2*)(counts + 4096);         // [4096 * 128] = 4 MB

  (void)hipMemsetAsync(counts, 0, kNCBlk * sizeof(uint32_t), stream);
  hipLaunchKernelGGL(fill_find_kernel, dim3(kGrid1), dim3(256), 0, stream, x,
                     counts, stash, out);
  hipLaunchKernelGGL(scatter_kernel, dim3(kNCBlk), dim3(256), 0, stream, x, counts,
                     stash, out);
}

// Round 14
// 31.709 us; speedup vs baseline: 7.6858x; 1.5261x over previous
//
#include <hip/hip_runtime.h>
#include <stdint.h>

// Radius-graph edge list, B=4, N=2048, cutoff 5.0.
// Output [2, B*P] int32: compacted valid edges (ascending flat index), -1 pad.
//
// Round-19: TLP, not ILP. r13's register double-buffer was defeated by the
// compiler (VGPR=36 < the 64 needed: prefetch arrays collapsed to a serial
// load-test chain, ~300 cy/candidate unchanged). Meanwhile r0's "slow" walk
// won on totals because 4094 blocks = 8 waves/SIMD hid every stall.
// So: 4x MORE finder blocks, 4x LESS work each. Finder = (batch, tile-pair,
// j-slice of 64): 576 blocks x 256 thr; each thread tests its i against 64
// LDS-staged j's. Finder waves co-schedule with 2048 fill blocks -> stalls
// hide under the 67 MB write stream.
//   K1 (2624 blk x 256): blocks 0-575 finder, 576-2623 contiguous -1 fill.
//   K2 scatter (4096 blk x 256): BYTE-IDENTICAL r10-r13 (validated 4x):
//       early-exit, 16 KB prefix, pf-rank order restore, exact fallback.
// Lessons pinned: r3 grid.sync 286us; r5 fence/nontemporal 233us; r6
// barrier-after-fill vmcnt drain; r8 same-line atomics; r9 decode VALU;
// r10/r11 pointer-chase; r12/r13 1-wave/SIMD finder = every stall exposed.

namespace {
constexpr int kB = 4;
constexpr int kN = 2048;
constexpr int kP = kN * (kN - 1) / 2;              // 2096128
constexpr long long kTotal = (long long)kB * kP;   // 8384512
constexpr float kCut2 = 25.0f;                     // 5.0^2
constexpr int kCap = 128;                          // stash slots per count-blk
constexpr int kNCBlk = 4096;                       // count-blocks (2048 pairs)
constexpr int kTile = 256;
constexpr int kNT = kN / kTile;                    // 8 tiles per dim
constexpr int kTPairs = kNT * (kNT + 1) / 2;       // 36 (ti <= tj)
constexpr int kJS = 4;                             // j-slices per tile-pair
constexpr int kSliceJ = kTile / kJS;               // 64 candidates per block
constexpr int kNF = kB * kTPairs * kJS;            // 576 finder blocks
constexpr int kFillBlk = 2048;
constexpr int kGrid1 = kNF + kFillBlk;             // 2624
constexpr int kFillN4 = (int)(2 * kTotal / 4);     // 4192256 int4s
constexpr int kFillPerBlk = 2048;                  // int4s per fill block
}  // namespace

// p in [0,P) -> (i,j), i<j, triu row-major (scatter fallback path only).
__device__ __forceinline__ void decode_pair(int p, int& i, int& j) {
  float t = sqrtf((float)(16769025 - 8 * p));
  int ii = (int)((4095.0f - t) * 0.5f);
  ii = ii < 0 ? 0 : (ii > kN - 2 ? kN - 2 : ii);
  while (ii > 0 && (ii * (4095 - ii)) / 2 > p) --ii;
  while (ii < kN - 2 && ((ii + 1) * (4094 - ii)) / 2 <= p) ++ii;
  i = ii;
  j = ii + 1 + (p - (ii * (4095 - ii)) / 2);
}

__device__ __forceinline__ bool pair_test(const float* __restrict__ x, int b, int p,
                                          int& gi, int& gj) {
  int i, j;
  decode_pair(p, i, j);
  const float* xb = x + (size_t)b * kN * 3;
  float dx = xb[3 * i + 0] - xb[3 * j + 0];
  float dy = xb[3 * i + 1] - xb[3 * j + 1];
  float dz = xb[3 * i + 2] - xb[3 * j + 2];
  gi = b * kN + i;
  gj = b * kN + j;
  return dx * dx + dy * dy + dz * dz <= kCut2;
}

// ---------------------------------------------------------------------------
// K1: blocks 0..575 = sliced tiled finder; blocks 576.. = -1 fill stream.
// ---------------------------------------------------------------------------
__global__ __launch_bounds__(256) void fill_find_kernel(
    const float* __restrict__ x, uint32_t* __restrict__ counts,
    int2* __restrict__ stash, int* __restrict__ out) {
  const int t = threadIdx.x;
  const int bid = blockIdx.x;

  if (bid >= kNF) {
    // Filler: contiguous 32 KB chunk of -1; stores issue from cycle 0,
    // nothing follows them (no barrier trap).
    const int4 m1 = make_int4(-1, -1, -1, -1);
    int4* o = (int4*)out;
    const int base = (bid - kNF) * kFillPerBlk;
#pragma unroll
    for (int s = 0; s < 8; ++s) {
      const int idx = base + s * 256 + t;
      if (idx < kFillN4) o[idx] = m1;
    }
    return;
  }

  // ---- Finder: block = (batch b, tile-pair u (ti<=tj), j-slice js) ----
  __shared__ float4 sp[kSliceJ];  // 64 staged j-candidates

  const int b = bid / (kTPairs * kJS);
  const int rem = bid - b * (kTPairs * kJS);
  const int u = rem / kJS;
  const int js = rem - u * kJS;
  int ti = 0, rowlen = kNT, acc = 0;
  while (acc + rowlen <= u) { acc += rowlen; --rowlen; ++ti; }
  const int tj = ti + (u - acc);

  const float3* __restrict__ xb3 = (const float3*)(x + (size_t)b * kN * 3);
  const int jbase = tj * kTile + js * kSliceJ;  // first j of this slice
  if (t < kSliceJ) {
    const float3 pj = xb3[jbase + t];
    sp[t] = make_float4(pj.x, pj.y, pj.z, 0.0f);
  }
  const int i = ti * kTile + t;
  const float3 pi = xb3[i];
  __syncthreads();  // before any big stores; finder does none (no vmcnt trap)

  const int gib = b << 11;            // global point-index base of batch b
  const uint32_t Ci = (uint32_t)((i * (4095 - i)) >> 1);  // C(i)
  const int cbb = b << 10;            // count-block base of batch b
  const bool diag = (ti == tj);       // block-uniform
  const int jrel0 = js * kSliceJ;     // j - tj*kTile offset of slice start

  // Emission: rare (~21 edges/block). Atomic (vmcnt) doesn't drain LDS
  // prefetch (lgkmcnt); slot-return dependency is paid only on hits.
  auto emit = [&](uint32_t m, int jb0) {
    do {
      const int k = __ffs(m) - 1;
      m &= m - 1;
      const int j = jbase + jb0 + k;
      const uint32_t pf = Ci + (uint32_t)(j - i - 1);
      const int cb = cbb + (int)(pf >> 11);
      const uint32_t slot = atomicAdd(&counts[cb], 1u);
      if (slot < (uint32_t)kCap)
        stash[(size_t)cb * kCap + slot] = make_int2(gib + i, gib + j);
    } while (m);
  };

  // 64 candidates, batched by 8 with mask-gated emission. TLP (several
  // finder+fill waves/SIMD) hides LDS latency; no fragile reg prefetch.
#pragma unroll
  for (int jb = 0; jb < kSliceJ; jb += 8) {
    uint32_t m = 0;
#pragma unroll
    for (int k = 0; k < 8; ++k) {
      const float4 c = sp[jb + k];
      const float dx = pi.x - c.x;
      const float dy = pi.y - c.y;
      const float dz = pi.z - c.z;
      const bool hit = (dx * dx + dy * dy + dz * dz <= kCut2) &&
                       (!diag || (jrel0 + jb + k) > t);
      m |= (uint32_t)hit << k;
    }
    if (m) emit(m, jb);
  }
}

// ---------------------------------------------------------------------------
// K2: scatter (r10-r13, validated 4x). Early-exit; prefix from 16 KB counts;
// pf-rank restores order; exact brute-force fallback if cnt > kCap.
// ---------------------------------------------------------------------------
__global__ __launch_bounds__(256) void scatter_kernel(
    const float* __restrict__ x, const uint32_t* __restrict__ counts,
    const int2* __restrict__ stash, int* __restrict__ out) {
  const int bid = blockIdx.x;
  const int t = threadIdx.x;

  const uint32_t cnt = counts[bid];
  if (cnt == 0) return;  // ~4090/4096 blocks

  const uint4* c4 = (const uint4*)counts;  // exactly 4096 entries
  uint32_t part = 0;
#pragma unroll
  for (int q = 0; q < 4; ++q) {
    uint4 v = c4[t * 4 + q];
    int i0 = t * 16 + q * 4;
    part += (i0 + 0 < bid) ? v.x : 0u;
    part += (i0 + 1 < bid) ? v.y : 0u;
    part += (i0 + 2 < bid) ? v.z : 0u;
    part += (i0 + 3 < bid) ? v.w : 0u;
  }
  for (int o = 32; o > 0; o >>= 1) part += __shfl_down(part, o, 64);
  __shared__ uint32_t wred[4];
  if ((t & 63) == 0) wred[t >> 6] = part;
  __syncthreads();
  if (t == 0) wred[0] = wred[0] + wred[1] + wred[2] + wred[3];
  __syncthreads();
  const uint32_t off = wred[0];

  if (cnt <= (uint32_t)kCap) {
    __shared__ int2 ebuf[kCap];
    __shared__ uint32_t pfb[kCap];
    for (uint32_t e = t; e < cnt; e += 256) {
      int2 v = stash[(size_t)bid * kCap + e];
      ebuf[e] = v;
      int i = v.x & 2047, j = v.y & 2047;
      pfb[e] = (uint32_t)((i * (4095 - i)) / 2 + (j - i - 1));
    }
    __syncthreads();
    for (uint32_t e = t; e < cnt; e += 256) {
      uint32_t mypf = pfb[e];
      uint32_t rank = 0;
      for (uint32_t f = 0; f < cnt; ++f) rank += (pfb[f] < mypf) ? 1u : 0u;
      out[off + rank] = ebuf[e].x;
      out[(size_t)kTotal + off + rank] = ebuf[e].y;
    }
    return;
  }

  // Fallback (cnt > kCap): exact ballot recompute of this count-block's
  // 2048-pair range.
  const int wave = t >> 6, lane = t & 63;
  const int b = bid >> 10;
  const int p0 = (bid & 1023) << 11;
  __shared__ uint32_t slot[32];
  unsigned long long masks[8];
  int gi[8], gj[8];
  bool fl[8];
#pragma unroll
  for (int k = 0; k < 8; ++k) {
    int p = p0 + k * 256 + t;
    fl[k] = (p < kP) && pair_test(x, b, p, gi[k], gj[k]);
    masks[k] = __ballot(fl[k]);
    if (lane == 0) slot[k * 4 + wave] = (uint32_t)__popcll(masks[k]);
  }
  __syncthreads();
  if (t == 0) {
    uint32_t run = 0;
    for (int s = 0; s < 32; ++s) {
      uint32_t c = slot[s];
      slot[s] = run;
      run += c;
    }
  }
  __syncthreads();
#pragma unroll
  for (int k = 0; k < 8; ++k) {
    if (fl[k]) {
      uint32_t pos = off + slot[k * 4 + wave] +
                     (uint32_t)__popcll(masks[k] & ((1ULL << lane) - 1ULL));
      out[pos] = gi[k];
      out[(size_t)kTotal + pos] = gj[k];
    }
  }
}

extern "C" void kernel_launch(void* const* d_in, const int* in_sizes, int n_in,
                              void* d_out, int out_size, void* d_ws, size_t ws_size,
                              hipStream_t stream) {
  const float* x = (const float*)d_in[0];
  int* out = (int*)d_out;
  uint32_t* counts = (uint32_t*)d_ws;           // [4096]
  int2* stash = (int2*)(counts + 4096);         // [4096 * 128] = 4 MB

  (void)hipMemsetAsync(counts, 0, kNCBlk * sizeof(uint32_t), stream);
  hipLaunchKernelGGL(fill_find_kernel, dim3(kGrid1), dim3(256), 0, stream, x,
                     counts, stash, out);
  hipLaunchKernelGGL(scatter_kernel, dim3(kNCBlk), dim3(256), 0, stream, x, counts,
                     stash, out);
}